// Round 7
// baseline (159.743 us; speedup 1.0000x reference)
//
#include <hip/hip_runtime.h>
#include <hip/hip_bf16.h>
#include <stdint.h>

#define SEQ   2048
#define DIM   512
#define BATCH 4

typedef __attribute__((ext_vector_type(8))) short  short8;
typedef __attribute__((ext_vector_type(4))) float  floatx4;

static __device__ __forceinline__ unsigned short f2b(float f) {
  return __builtin_bit_cast(unsigned short, __float2bfloat16(f));
}

// async 16B/lane global->LDS (global_load_lds_dwordx4)
static __device__ __forceinline__ void gll16(const void* g, void* l) {
  __builtin_amdgcn_global_load_lds(
      (__attribute__((address_space(1))) void*)(uintptr_t)g,
      (__attribute__((address_space(3))) void*)l, 16, 0, 0);
}

// ---------------------------------------------------------------------------
// Fragment-linear layout (verified): logical [R rows][K] bf16 matrix as 1KB
// fragments of 16 rows x 32 k; frag index = rt*TK + kt; within a frag, lane l
// owns bytes l*16..+15 = MFMA operand row rt*16+(l&15), k octet (l>>4).
// ---------------------------------------------------------------------------

// Pipelined fragment GEMM v2: 3-slot LDS ring, depth-2 prefetch, counted
// vmcnt ladder (u -> 0), PH MFMA phases per slot.  Staging is distributed
// flatly across NW waves (u = U/NW gll16 per wave per slot), all issued in
// phase 0.  Per phase: {ds_read chunk -> barrier -> lgkmcnt(0) -> setprio(1)
// MFMA setprio(0) -> barrier/ladder}.  Callers guarantee any VMEM issued
// before entry is complete-or-conservative w.r.t. the counted waits (earlier
// loads only make the waits stricter, never under-wait).
template <int AF, int BF, int WM, int WN, int KC, int PH, int KIT, int NW>
__device__ __forceinline__ void fgemm_v2(
    const char* __restrict__ A, int rtA0, int TKA,
    const char* __restrict__ B, int rtB0, int TKB,
    char* lds, floatx4 (&acc)[AF / WM][BF / WN])
{
  constexpr int AWF  = AF / WM, BWF = BF / WN;
  constexpr int SLOT = (AF + BF) * KC * 1024;
  constexpr int U    = KC * (AF + BF);       // gll16 per slot per block
  constexpr int UW   = U / NW;               // gll16 per wave per slot
  constexpr int AC   = AWF / PH;             // A-frag rows per MFMA phase
  static_assert(KIT >= 3, "pipeline needs >=3 K-slots");
  static_assert(U % NW == 0, "stage units must divide waves");
  static_assert(AWF % PH == 0, "phase split must divide A rows");
  const int tid = threadIdx.x;
  const int w = tid >> 6, l = tid & 63;
  const int wm = w % WM, wn = w / WM;

  auto stage_slot = [&](char* dst, int kt) {
#pragma unroll
    for (int e = 0; e < UW; ++e) {
      const int g = w * UW + e;              // flat unit id (wave-uniform)
      if (g < KC * AF) {
        const int c = g / AF, f = g % AF;
        gll16(A + (((size_t)(rtA0 + f) * TKA + kt * KC + c) << 10) + l * 16,
              dst + (c * AF + f) * 1024 + l * 16);
      } else {
        const int h = g - KC * AF;
        const int c = h / BF, f = h % BF;
        gll16(B + (((size_t)(rtB0 + f) * TKB + kt * KC + c) << 10) + l * 16,
              dst + (KC * AF + c * BF + f) * 1024 + l * 16);
      }
    }
  };

  // Prologue: 2 slots in flight; publish slot 0 (wait only its UW loads).
  stage_slot(lds, 0);
  stage_slot(lds + SLOT, 1);
  asm volatile("s_waitcnt vmcnt(%0) lgkmcnt(0)\ns_barrier" :: "n"(UW) : "memory");

  short8 bf[KC][BWF];
  int cs = 0;                               // current ring slot (mod 3)
#pragma unroll 2
  for (int kt = 0; kt < KIT; ++kt) {
    const char* bA = lds + cs * SLOT;
    const char* bB = bA + KC * AF * 1024;
    int ns = cs - 1; if (ns < 0) ns = 2;    // slot of kt+2 == (cs+2)%3
    char* pdst = lds + ns * SLOT;
#pragma unroll
    for (int p = 0; p < PH; ++p) {
      short8 af[KC][AC];
#pragma unroll
      for (int c = 0; c < KC; ++c)
#pragma unroll
        for (int i = 0; i < AC; ++i)
          af[c][i] = *(const short8*)(bA + (c * AF + wm * AWF + p * AC + i) * 1024 + l * 16);
      if (p == 0) {
#pragma unroll
        for (int c = 0; c < KC; ++c)
#pragma unroll
          for (int j = 0; j < BWF; ++j)
            bf[c][j] = *(const short8*)(bB + (c * BF + wn * BWF + j) * 1024 + l * 16);
        if (kt + 2 < KIT) stage_slot(pdst, kt + 2);   // depth-2 prefetch
      }

      asm volatile("s_barrier" ::: "memory");
      asm volatile("s_waitcnt lgkmcnt(0)" ::: "memory");
      __builtin_amdgcn_s_setprio(1);
#pragma unroll
      for (int c = 0; c < KC; ++c)
#pragma unroll
        for (int i = 0; i < AC; ++i)
#pragma unroll
          for (int j = 0; j < BWF; ++j)
            acc[p * AC + i][j] = __builtin_amdgcn_mfma_f32_16x16x32_bf16(
                af[c][i], bf[c][j], acc[p * AC + i][j], 0, 0, 0);
      __builtin_amdgcn_s_setprio(0);

      if (p == PH - 1) {        // slot-closing barrier: counted vmcnt ladder
        if (kt + 2 < KIT)
          asm volatile("s_waitcnt vmcnt(%0)\ns_barrier" :: "n"(UW) : "memory");
        else if (kt + 1 < KIT)
          asm volatile("s_waitcnt vmcnt(0)\ns_barrier" ::: "memory");
        // last slot: fall through to epilogue (all gll16 retired by ladder)
      } else {
        asm volatile("s_barrier" ::: "memory");
      }
    }
    ++cs; if (cs == 3) cs = 0;
  }
}

// ---- K0: setup: X->XbF frags, W->WF frags (transposed) --------------------
__global__ __launch_bounds__(256) void setup_kernel(
    const float* __restrict__ X, const float* __restrict__ Wq,
    const float* __restrict__ Wk, const float* __restrict__ Wv,
    short8* __restrict__ XbF, short8* __restrict__ WF)
{
  const int flat = blockIdx.x * 256 + threadIdx.x;   // 0..524287
  {
    const int tile = flat >> 6, l = flat & 63;
    const int row = (tile >> 4) * 16 + (l & 15);
    const int k0  = (tile & 15) * 32 + (l >> 4) * 8;
    const float4 v0 = *(const float4*)(X + (size_t)row * DIM + k0);
    const float4 v1 = *(const float4*)(X + (size_t)row * DIM + k0 + 4);
    short8 o;
    o[0] = (short)f2b(v0.x); o[1] = (short)f2b(v0.y);
    o[2] = (short)f2b(v0.z); o[3] = (short)f2b(v0.w);
    o[4] = (short)f2b(v1.x); o[5] = (short)f2b(v1.y);
    o[6] = (short)f2b(v1.z); o[7] = (short)f2b(v1.w);
    XbF[flat] = o;
  }
  if (flat < 3 * 32768) {                            // W -> WF (rows=n, K=k)
    const int z = flat >> 15, within = flat & 32767;
    const float* W = (z == 0) ? Wq : (z == 1) ? Wk : Wv;
    const int tile = within >> 6, l = within & 63;
    const int n  = (tile >> 4) * 16 + (l & 15);
    const int k0 = (tile & 15) * 32 + (l >> 4) * 8;
    short8 o;
#pragma unroll
    for (int e = 0; e < 8; ++e)
      o[e] = (short)f2b(W[(size_t)(k0 + e) * DIM + n]);
    WF[flat] = o;
  }
}

// ---- K1: QKV. 256x128 tiles, 8 waves, 72KB -> 2 blocks/CU (16 waves/CU). --
__global__ __launch_bounds__(512, 4) void qkv_kernel(
    const short8* __restrict__ XbF, const short8* __restrict__ WF,
    const float* __restrict__ bq, const float* __restrict__ bk,
    const float* __restrict__ bv,
    unsigned short* __restrict__ QF, unsigned short* __restrict__ KF,
    unsigned short* __restrict__ VF)
{
  __shared__ char lds[73728];   // 3 x 24 KB ring
  const int blk = blockIdx.x;                    // 0..383
  const int n = (blk & 7) * 48 + (blk >> 3);     // chunked: 48 per XCD
  const int lane = threadIdx.x & 63, w = threadIdx.x >> 6;
  const int wm = w & 1, wn = w >> 1;             // WM=2, WN=4
  const char* Xc = (const char*)XbF;
  const char* Wc = (const char*)WF;
  floatx4 acc[8][2] = {};

  if (n < 256) {
    const int z = n >> 7, y = (n >> 6) & 1, x = n & 63;   // x: s-tile(128)
    fgemm_v2<16, 8, 2, 4, 1, 2, 16, 8>(Wc + (size_t)z * 524288, y * 16, 16,
                                       Xc, x * 8, 16, lds, acc);
    const float* bias = z ? bk : bq;
    unsigned short* OF = z ? KF : QF;
    const int dbase = y * 256 + wm * 128;
    const int sbase = x * 128 + wn * 32;
#pragma unroll
    for (int i2 = 0; i2 < 8; ++i2) {
      const int d0 = dbase + i2 * 16 + (lane >> 4) * 4;
      const float4 b4 = *(const float4*)(bias + d0);
#pragma unroll
      for (int j = 0; j < 2; ++j) {
        const int s = sbase + j * 16 + (lane & 15);
        ushort4 pk;
        pk.x = f2b(acc[i2][j][0] + b4.x);
        pk.y = f2b(acc[i2][j][1] + b4.y);
        pk.z = f2b(acc[i2][j][2] + b4.z);
        pk.w = f2b(acc[i2][j][3] + b4.w);
        *(ushort4*)(OF + (size_t)((s >> 4) * 16 + (d0 >> 5)) * 512 +
                    ((((d0 & 31) >> 3) << 4) | (s & 15)) * 8 + (d0 & 7)) = pk;
      }
    }
  } else {
    const int m = n - 256;                         // 0..127
    const int x = m >> 2, y = m & 3;               // x: s-tile(256), y: d-tile(128)
    fgemm_v2<16, 8, 2, 4, 1, 2, 16, 8>(Xc, x * 16, 16,
                                       Wc + 2 * 524288, y * 8, 16, lds, acc);
    const int sbase = x * 256 + wm * 128;
    const int dbase = y * 128 + wn * 32;
#pragma unroll
    for (int i2 = 0; i2 < 8; ++i2) {
      const int s0 = sbase + i2 * 16 + (lane >> 4) * 4;
      const int bt = s0 >> 11, t0 = s0 & 2047;
#pragma unroll
      for (int j = 0; j < 2; ++j) {
        const int d = dbase + j * 16 + (lane & 15);
        const float bn = bv[d];
        ushort4 pk;
        pk.x = f2b(acc[i2][j][0] + bn);
        pk.y = f2b(acc[i2][j][1] + bn);
        pk.z = f2b(acc[i2][j][2] + bn);
        pk.w = f2b(acc[i2][j][3] + bn);
        *(ushort4*)(VF + (size_t)bt * DIM * SEQ +
                    (size_t)((d >> 4) * 64 + (t0 >> 5)) * 512 +
                    ((((t0 & 31) >> 3) << 4) | (d & 15)) * 8 + (t0 & 7)) = pk;
      }
    }
  }
}

// ---- K2: S^T = K Q^T, 256t x 128s tiles, 8 waves, 2 blocks/CU. ------------
// 512 blocks, chunked XCD (64/XCD => half batch per XCD, Q+K L2-fit).
__global__ __launch_bounds__(512, 4) void scores_kernel(
    const unsigned short* __restrict__ QF, const unsigned short* __restrict__ KF,
    unsigned short* __restrict__ ScF, float* __restrict__ prow)
{
  __shared__ char lds[73728];   // 3 x 24 KB ring
  const int blk = blockIdx.x;                    // 0..511
  const int n = (blk & 7) * 64 + (blk >> 3);
  const int b = n >> 7, t = n & 127;
  const int y = t >> 4, x = t & 15;              // y: t-tile(256), x: s-tile(128)
  const int lane = threadIdx.x & 63, w = threadIdx.x >> 6;
  const int wm = w & 1, wn = w >> 1;             // WM=2, WN=4
  floatx4 acc[8][2] = {};
  fgemm_v2<16, 8, 2, 4, 1, 2, 16, 8>((const char*)KF + (size_t)b * 2097152, y * 16, 16,
                                     (const char*)QF + (size_t)b * 2097152, x * 8, 16,
                                     lds, acc);

  unsigned short* S = ScF + (size_t)b * SEQ * SEQ;
  const float scale = 0.044194173824159216f;  // 1/sqrt(512)
  const int tbase = y * 256 + wm * 128;
  const int sbase = x * 128 + wn * 32;
  float colsum[2] = {0.f, 0.f};
#pragma unroll
  for (int i2 = 0; i2 < 8; ++i2) {
    const int t0 = tbase + i2 * 16 + (lane >> 4) * 4;
#pragma unroll
    for (int j = 0; j < 2; ++j) {
      const int s = sbase + j * 16 + (lane & 15);
      float e0 = __expf(acc[i2][j][0] * scale);
      float e1 = __expf(acc[i2][j][1] * scale);
      float e2 = __expf(acc[i2][j][2] * scale);
      float e3 = __expf(acc[i2][j][3] * scale);
      colsum[j] += (e0 + e1) + (e2 + e3);
      ushort4 pk;
      pk.x = f2b(e0); pk.y = f2b(e1); pk.z = f2b(e2); pk.w = f2b(e3);
      *(ushort4*)(S + (size_t)((s >> 4) * 64 + (t0 >> 5)) * 512 +
                  ((((t0 & 31) >> 3) << 4) | (s & 15)) * 8 + (t0 & 7)) = pk;
    }
  }
#pragma unroll
  for (int j = 0; j < 2; ++j) {
    colsum[j] += __shfl_xor(colsum[j], 16, 64);
    colsum[j] += __shfl_xor(colsum[j], 32, 64);
  }
  if (lane < 16) {   // partial rowsum slice q = y*2+wm (t-range q*128..+127)
    float* dst = prow + ((size_t)(y * 2 + wm) * BATCH + b) * SEQ + sbase + lane;
#pragma unroll
    for (int j = 0; j < 2; ++j) dst[j * 16] = colsum[j];
  }
}

// ---- K3: out[s][d] = (ScF . VF) / rowsum[s]; 128s x 64d tile, BK=64. ------
// 8 waves, 2 blocks/CU, 512 blocks, chunked XCD.
__global__ __launch_bounds__(512, 4) void pv_kernel(
    const unsigned short* __restrict__ ScF, const unsigned short* __restrict__ VF,
    const float* __restrict__ prow, float* __restrict__ out)
{
  __shared__ char lds[73728];   // 3 x 24 KB ring
  __shared__ float rinv[128];
  const int blk = blockIdx.x;                    // 0..511
  const int n = (blk & 7) * 64 + (blk >> 3);
  const int b = n >> 7, r = n & 127;
  const int x = r >> 3, y = r & 7;               // x: s-stripe(128), y: d-tile(64)
  const int t = threadIdx.x;
  if (t < 128) {   // rowsum = sum of 16 partial slices (pre-pass loads only
    const int s = x * 128 + t;   // make the counted waits conservative)
    float rr = 0.f;
#pragma unroll
    for (int q = 0; q < 16; ++q) rr += prow[((size_t)q * BATCH + b) * SEQ + s];
    rinv[t] = 1.f / rr;
  }
  const int lane = threadIdx.x & 63, w = threadIdx.x >> 6;
  const int wm = w & 1, wn = w >> 1;             // WM=2, WN=4
  floatx4 acc[4][1] = {};
  fgemm_v2<8, 4, 2, 4, 2, 2, 32, 8>((const char*)ScF + (size_t)b * 8388608, x * 8, 64,
                                    (const char*)VF + (size_t)b * 2097152, y * 4, 64,
                                    lds, acc);

  const int mbase = x * 128 + wm * 64;
  const int dbase = y * 64 + wn * 16;
#pragma unroll
  for (int i2 = 0; i2 < 4; ++i2) {
    const int r0 = wm * 64 + i2 * 16 + (lane >> 4) * 4;
    const int m0 = mbase + i2 * 16 + (lane >> 4) * 4;
    const float inv0 = rinv[r0], inv1 = rinv[r0 + 1], inv2 = rinv[r0 + 2], inv3 = rinv[r0 + 3];
    const int d = dbase + (lane & 15);
    float* o = out + ((size_t)b * SEQ + m0) * DIM + d;
    o[0 * DIM] = acc[i2][0][0] * inv0;
    o[1 * DIM] = acc[i2][0][1] * inv1;
    o[2 * DIM] = acc[i2][0][2] * inv2;
    o[3 * DIM] = acc[i2][0][3] * inv3;
  }
}

extern "C" void kernel_launch(void* const* d_in, const int* in_sizes, int n_in,
                              void* d_out, int out_size, void* d_ws, size_t ws_size,
                              hipStream_t stream) {
  const float* X  = (const float*)d_in[0];
  const float* Wq = (const float*)d_in[1];
  const float* bq = (const float*)d_in[2];
  const float* Wk = (const float*)d_in[3];
  const float* bk = (const float*)d_in[4];
  const float* Wv = (const float*)d_in[5];
  const float* bv = (const float*)d_in[6];
  float* out = (float*)d_out;
  char* ws = (char*)d_ws;

  // workspace layout (bytes). prow aliases XbF (XbF dead after qkv; prow is
  // fully written by scores before pv reads it).
  short8* XbF = (short8*)(ws + 0);                    //  8 MB   (rows=b*S+s, K=512)
  float*  prow = (float*)(ws + 0);                    // 512 KB  [16][B][SEQ] partial rowsums
  short8* WF  = (short8*)(ws + 8388608);              //  1.5 MB (rows=n, K=512, x3)
  unsigned short* QF  = (unsigned short*)(ws + 9961472);   //  8 MB (rows=s, K=d)
  unsigned short* KF  = (unsigned short*)(ws + 18350080);  //  8 MB (rows=s, K=d)
  unsigned short* VF  = (unsigned short*)(ws + 26738688);  //  8 MB (rows=d, K=t, per b)
  unsigned short* ScF = (unsigned short*)(ws + 35127296);  // 32 MB (rows=s, K=t, per b)

  setup_kernel<<<dim3(2048), 256, 0, stream>>>(X, Wq, Wk, Wv, XbF, WF);
  qkv_kernel<<<dim3(384), 512, 0, stream>>>(XbF, WF, bq, bk, bv, QF, KF, VF);
  scores_kernel<<<dim3(512), 512, 0, stream>>>(QF, KF, ScF, prow);
  pv_kernel<<<dim3(512), 512, 0, stream>>>(ScF, VF, prow, out);
}

// Round 8
// 155.225 us; speedup vs baseline: 1.0291x; 1.0291x over previous
//
#include <hip/hip_runtime.h>
#include <hip/hip_bf16.h>
#include <stdint.h>

#define SEQ   2048
#define DIM   512
#define BATCH 4

typedef __attribute__((ext_vector_type(8))) short  short8;
typedef __attribute__((ext_vector_type(4))) float  floatx4;

static __device__ __forceinline__ unsigned short f2b(float f) {
  return __builtin_bit_cast(unsigned short, __float2bfloat16(f));
}

// ---------------------------------------------------------------------------
// Fragment-linear layout (verified): logical [R rows][K] bf16 matrix as 1KB
// fragments of 16 rows x 32 k; frag index = rt*TK + kt; within a frag, lane l
// owns bytes l*16..+15 = MFMA operand row rt*16+(l&15), k octet (l>>4).
//
// Direct-streaming GEMM: the global fragment image IS the MFMA operand
// layout, so each wave loads its fragments straight to VGPRs (coalesced
// global_load_dwordx4, 1KB/wave/frag) and feeds MFMA.  No LDS, no barriers,
// no waitcnt asm.  Cross-wave fragment reuse is served by L1 (per-step
// working set ~24KB < 32KB; co-wm waves issue identical addresses) and L2.
// Latency is hidden by compiler pipelining + 8-16 waves/CU of TLP with no
// sync points to re-expose it.
// ---------------------------------------------------------------------------
template <int AF, int BF, int WM, int WN, int KIT, bool DB>
__device__ __forceinline__ void fgemm_d(
    const char* __restrict__ A, int rtA0, int TKA,
    const char* __restrict__ B, int rtB0, int TKB,
    floatx4 (&acc)[AF / WM][BF / WN])
{
  constexpr int AWF = AF / WM, BWF = BF / WN;
  const int tid = threadIdx.x;
  const int w = tid >> 6, l = tid & 63;
  const int wm = w % WM, wn = w / WM;
  const char* Ab = A + (((size_t)(rtA0 + wm * AWF) * TKA) << 10) + l * 16;
  const char* Bb = B + (((size_t)(rtB0 + wn * BWF) * TKB) << 10) + l * 16;

  auto lda = [&](short8 (&af)[AWF], int kt) {
#pragma unroll
    for (int i = 0; i < AWF; ++i)
      af[i] = *(const short8*)(Ab + (((size_t)i * TKA + kt) << 10));
  };
  auto ldb = [&](short8 (&bf)[BWF], int kt) {
#pragma unroll
    for (int j = 0; j < BWF; ++j)
      bf[j] = *(const short8*)(Bb + (((size_t)j * TKB + kt) << 10));
  };
  auto domfma = [&](short8 (&af)[AWF], short8 (&bf)[BWF]) {
#pragma unroll
    for (int i = 0; i < AWF; ++i)
#pragma unroll
      for (int j = 0; j < BWF; ++j)
        acc[i][j] = __builtin_amdgcn_mfma_f32_16x16x32_bf16(af[i], bf[j], acc[i][j], 0, 0, 0);
  };

  if constexpr (DB) {            // manual 2-deep pipeline (static indexing)
    short8 a0[AWF], b0[BWF], a1[AWF], b1[BWF];
    lda(a0, 0); ldb(b0, 0);
    static_assert(KIT % 2 == 0, "DB path needs even KIT");
#pragma unroll 2
    for (int kt = 0; kt < KIT; kt += 2) {
      lda(a1, kt + 1); ldb(b1, kt + 1);
      domfma(a0, b0);
      if (kt + 2 < KIT) { lda(a0, kt + 2); ldb(b0, kt + 2); }
      domfma(a1, b1);
    }
  } else {
#pragma unroll 2
    for (int kt = 0; kt < KIT; ++kt) {
      short8 af[AWF], bf[BWF];
      lda(af, kt); ldb(bf, kt);
      domfma(af, bf);
    }
  }
}

// ---- K0: setup: X->XbF frags, W->WF frags (transposed) --------------------
__global__ __launch_bounds__(256) void setup_kernel(
    const float* __restrict__ X, const float* __restrict__ Wq,
    const float* __restrict__ Wk, const float* __restrict__ Wv,
    short8* __restrict__ XbF, short8* __restrict__ WF)
{
  const int flat = blockIdx.x * 256 + threadIdx.x;   // 0..524287
  {
    const int tile = flat >> 6, l = flat & 63;
    const int row = (tile >> 4) * 16 + (l & 15);
    const int k0  = (tile & 15) * 32 + (l >> 4) * 8;
    const float4 v0 = *(const float4*)(X + (size_t)row * DIM + k0);
    const float4 v1 = *(const float4*)(X + (size_t)row * DIM + k0 + 4);
    short8 o;
    o[0] = (short)f2b(v0.x); o[1] = (short)f2b(v0.y);
    o[2] = (short)f2b(v0.z); o[3] = (short)f2b(v0.w);
    o[4] = (short)f2b(v1.x); o[5] = (short)f2b(v1.y);
    o[6] = (short)f2b(v1.z); o[7] = (short)f2b(v1.w);
    XbF[flat] = o;
  }
  if (flat < 3 * 32768) {                            // W -> WF (rows=n, K=k)
    const int z = flat >> 15, within = flat & 32767;
    const float* W = (z == 0) ? Wq : (z == 1) ? Wk : Wv;
    const int tile = within >> 6, l = within & 63;
    const int n  = (tile >> 4) * 16 + (l & 15);
    const int k0 = (tile & 15) * 32 + (l >> 4) * 8;
    short8 o;
#pragma unroll
    for (int e = 0; e < 8; ++e)
      o[e] = (short)f2b(W[(size_t)(k0 + e) * DIM + n]);
    WF[flat] = o;
  }
}

// ---- K1: QKV. 256x128 tiles, 8 waves (WM=4,WN=2), direct streaming. -------
__global__ __launch_bounds__(512, 2) void qkv_kernel(
    const short8* __restrict__ XbF, const short8* __restrict__ WF,
    const float* __restrict__ bq, const float* __restrict__ bk,
    const float* __restrict__ bv,
    unsigned short* __restrict__ QF, unsigned short* __restrict__ KF,
    unsigned short* __restrict__ VF)
{
  const int blk = blockIdx.x;                    // 0..383
  const int n = (blk & 7) * 48 + (blk >> 3);     // chunked: 48 per XCD
  const int lane = threadIdx.x & 63, w = threadIdx.x >> 6;
  const int wm = w & 3, wn = w >> 2;             // WM=4, WN=2
  const char* Xc = (const char*)XbF;
  const char* Wc = (const char*)WF;
  floatx4 acc[4][4] = {};

  if (n < 256) {
    const int z = n >> 7, y = (n >> 6) & 1, x = n & 63;   // x: s-tile(128)
    fgemm_d<16, 8, 4, 2, 16, false>(Wc + (size_t)z * 524288, y * 16, 16,
                                    Xc, x * 8, 16, acc);
    const float* bias = z ? bk : bq;
    unsigned short* OF = z ? KF : QF;
    const int dbase = y * 256 + wm * 64;
    const int sbase = x * 128 + wn * 64;
#pragma unroll
    for (int i2 = 0; i2 < 4; ++i2) {
      const int d0 = dbase + i2 * 16 + (lane >> 4) * 4;
      const float4 b4 = *(const float4*)(bias + d0);
#pragma unroll
      for (int j = 0; j < 4; ++j) {
        const int s = sbase + j * 16 + (lane & 15);
        ushort4 pk;
        pk.x = f2b(acc[i2][j][0] + b4.x);
        pk.y = f2b(acc[i2][j][1] + b4.y);
        pk.z = f2b(acc[i2][j][2] + b4.z);
        pk.w = f2b(acc[i2][j][3] + b4.w);
        *(ushort4*)(OF + (size_t)((s >> 4) * 16 + (d0 >> 5)) * 512 +
                    ((((d0 & 31) >> 3) << 4) | (s & 15)) * 8 + (d0 & 7)) = pk;
      }
    }
  } else {
    const int m = n - 256;                         // 0..127
    const int x = m >> 2, y = m & 3;               // x: s-tile(256), y: d-tile(128)
    fgemm_d<16, 8, 4, 2, 16, false>(Xc, x * 16, 16,
                                    Wc + 2 * 524288, y * 8, 16, acc);
    const int sbase = x * 256 + wm * 64;
    const int dbase = y * 128 + wn * 64;
#pragma unroll
    for (int i2 = 0; i2 < 4; ++i2) {
      const int s0 = sbase + i2 * 16 + (lane >> 4) * 4;
      const int bt = s0 >> 11, t0 = s0 & 2047;
#pragma unroll
      for (int j = 0; j < 4; ++j) {
        const int d = dbase + j * 16 + (lane & 15);
        const float bn = bv[d];
        ushort4 pk;
        pk.x = f2b(acc[i2][j][0] + bn);
        pk.y = f2b(acc[i2][j][1] + bn);
        pk.z = f2b(acc[i2][j][2] + bn);
        pk.w = f2b(acc[i2][j][3] + bn);
        *(ushort4*)(VF + (size_t)bt * DIM * SEQ +
                    (size_t)((d >> 4) * 64 + (t0 >> 5)) * 512 +
                    ((((t0 & 31) >> 3) << 4) | (d & 15)) * 8 + (t0 & 7)) = pk;
      }
    }
  }
}

// ---- K2: S^T = K Q^T, 256t x 128s tiles, 8 waves (WM=4,WN=2), direct. -----
// 512 blocks (2/CU, 16 waves/CU).  prow: 32 slices of 64-t partial rowsums.
__global__ __launch_bounds__(512, 2) void scores_kernel(
    const unsigned short* __restrict__ QF, const unsigned short* __restrict__ KF,
    unsigned short* __restrict__ ScF, float* __restrict__ prow)
{
  const int blk = blockIdx.x;                    // 0..511
  const int n = (blk & 7) * 64 + (blk >> 3);
  const int b = n >> 7, t = n & 127;
  const int y = t >> 4, x = t & 15;              // y: t-tile(256), x: s-tile(128)
  const int lane = threadIdx.x & 63, w = threadIdx.x >> 6;
  const int wm = w & 3, wn = w >> 2;             // WM=4, WN=2
  floatx4 acc[4][4] = {};
  fgemm_d<16, 8, 4, 2, 16, false>((const char*)KF + (size_t)b * 2097152, y * 16, 16,
                                  (const char*)QF + (size_t)b * 2097152, x * 8, 16,
                                  acc);

  unsigned short* S = ScF + (size_t)b * SEQ * SEQ;
  const float scale = 0.044194173824159216f;  // 1/sqrt(512)
  const int tbase = y * 256 + wm * 64;
  const int sbase = x * 128 + wn * 64;
  float colsum[4] = {0.f, 0.f, 0.f, 0.f};
#pragma unroll
  for (int i2 = 0; i2 < 4; ++i2) {
    const int t0 = tbase + i2 * 16 + (lane >> 4) * 4;
#pragma unroll
    for (int j = 0; j < 4; ++j) {
      const int s = sbase + j * 16 + (lane & 15);
      float e0 = __expf(acc[i2][j][0] * scale);
      float e1 = __expf(acc[i2][j][1] * scale);
      float e2 = __expf(acc[i2][j][2] * scale);
      float e3 = __expf(acc[i2][j][3] * scale);
      colsum[j] += (e0 + e1) + (e2 + e3);
      ushort4 pk;
      pk.x = f2b(e0); pk.y = f2b(e1); pk.z = f2b(e2); pk.w = f2b(e3);
      *(ushort4*)(S + (size_t)((s >> 4) * 64 + (t0 >> 5)) * 512 +
                  ((((t0 & 31) >> 3) << 4) | (s & 15)) * 8 + (t0 & 7)) = pk;
    }
  }
#pragma unroll
  for (int j = 0; j < 4; ++j) {
    colsum[j] += __shfl_xor(colsum[j], 16, 64);
    colsum[j] += __shfl_xor(colsum[j], 32, 64);
  }
  if (lane < 16) {   // partial rowsum slice q = y*4+wm (t-range q*64..+63)
    float* dst = prow + ((size_t)(y * 4 + wm) * BATCH + b) * SEQ + sbase + lane;
#pragma unroll
    for (int j = 0; j < 4; ++j) dst[j * 16] = colsum[j];
  }
}

// ---- K3: out[s][d] = (ScF . VF) / rowsum[s]; 128s x 128d, direct 2-deep. --
// 256 blocks, 8 waves (WM=4,WN=2).  One barrier (rinv broadcast) only.
__global__ __launch_bounds__(512, 2) void pv_kernel(
    const unsigned short* __restrict__ ScF, const unsigned short* __restrict__ VF,
    const float* __restrict__ prow, float* __restrict__ out)
{
  __shared__ float rinv[128];
  const int blk = blockIdx.x;                    // 0..255
  const int n = (blk & 7) * 32 + (blk >> 3);
  const int b = n >> 6, r = n & 63;
  const int x = r >> 2, y = r & 3;               // x: s-stripe(128), y: d-tile(128)
  const int t = threadIdx.x;
  if (t < 128) {   // rowsum = sum of 32 partial slices
    const int s = x * 128 + t;
    float rr = 0.f;
#pragma unroll
    for (int q = 0; q < 32; ++q) rr += prow[((size_t)q * BATCH + b) * SEQ + s];
    rinv[t] = 1.f / rr;
  }
  __syncthreads();
  const int lane = threadIdx.x & 63, w = threadIdx.x >> 6;
  const int wm = w & 3, wn = w >> 2;             // WM=4, WN=2
  floatx4 acc[2][4] = {};
  fgemm_d<8, 8, 4, 2, 64, true>((const char*)ScF + (size_t)b * 8388608, x * 8, 64,
                                (const char*)VF + (size_t)b * 2097152, y * 8, 64,
                                acc);

  const int mbase = x * 128 + wm * 32;
  const int dbase = y * 128 + wn * 64;
#pragma unroll
  for (int i2 = 0; i2 < 2; ++i2) {
    const int r0 = wm * 32 + i2 * 16 + (lane >> 4) * 4;
    const int m0 = mbase + i2 * 16 + (lane >> 4) * 4;
    const float inv0 = rinv[r0], inv1 = rinv[r0 + 1], inv2 = rinv[r0 + 2], inv3 = rinv[r0 + 3];
#pragma unroll
    for (int j = 0; j < 4; ++j) {
      const int d = dbase + j * 16 + (lane & 15);
      float* o = out + ((size_t)b * SEQ + m0) * DIM + d;
      o[0 * DIM] = acc[i2][j][0] * inv0;
      o[1 * DIM] = acc[i2][j][1] * inv1;
      o[2 * DIM] = acc[i2][j][2] * inv2;
      o[3 * DIM] = acc[i2][j][3] * inv3;
    }
  }
}

extern "C" void kernel_launch(void* const* d_in, const int* in_sizes, int n_in,
                              void* d_out, int out_size, void* d_ws, size_t ws_size,
                              hipStream_t stream) {
  const float* X  = (const float*)d_in[0];
  const float* Wq = (const float*)d_in[1];
  const float* bq = (const float*)d_in[2];
  const float* Wk = (const float*)d_in[3];
  const float* bk = (const float*)d_in[4];
  const float* Wv = (const float*)d_in[5];
  const float* bv = (const float*)d_in[6];
  float* out = (float*)d_out;
  char* ws = (char*)d_ws;

  // workspace layout (bytes). prow aliases XbF (XbF dead after qkv; prow is
  // fully written by scores before pv reads it).  prow: [32][B][SEQ] f32.
  short8* XbF = (short8*)(ws + 0);                    //  8 MB   (rows=b*S+s, K=512)
  float*  prow = (float*)(ws + 0);                    //  1 MB   partial rowsums
  short8* WF  = (short8*)(ws + 8388608);              //  1.5 MB (rows=n, K=512, x3)
  unsigned short* QF  = (unsigned short*)(ws + 9961472);   //  8 MB (rows=s, K=d)
  unsigned short* KF  = (unsigned short*)(ws + 18350080);  //  8 MB (rows=s, K=d)
  unsigned short* VF  = (unsigned short*)(ws + 26738688);  //  8 MB (rows=d, K=t, per b)
  unsigned short* ScF = (unsigned short*)(ws + 35127296);  // 32 MB (rows=s, K=t, per b)

  setup_kernel<<<dim3(2048), 256, 0, stream>>>(X, Wq, Wk, Wv, XbF, WF);
  qkv_kernel<<<dim3(384), 512, 0, stream>>>(XbF, WF, bq, bk, bv, QF, KF, VF);
  scores_kernel<<<dim3(512), 512, 0, stream>>>(QF, KF, ScF, prow);
  pv_kernel<<<dim3(256), 512, 0, stream>>>(ScF, VF, prow, out);
}

// Round 9
// 140.181 us; speedup vs baseline: 1.1395x; 1.1073x over previous
//
#include <hip/hip_runtime.h>
#include <hip/hip_bf16.h>
#include <stdint.h>

#define SEQ   2048
#define DIM   512
#define BATCH 4

typedef __attribute__((ext_vector_type(8))) short  short8;
typedef __attribute__((ext_vector_type(4))) float  floatx4;

static __device__ __forceinline__ unsigned short f2b(float f) {
  return __builtin_bit_cast(unsigned short, __float2bfloat16(f));
}

// async 16B/lane global->LDS (global_load_lds_dwordx4)
static __device__ __forceinline__ void gll16(const void* g, void* l) {
  __builtin_amdgcn_global_load_lds(
      (__attribute__((address_space(1))) void*)(uintptr_t)g,
      (__attribute__((address_space(3))) void*)l, 16, 0, 0);
}

// ---------------------------------------------------------------------------
// Fragment-linear layout (verified): logical [R rows][K] bf16 matrix as 1KB
// fragments of 16 rows x 32 k; frag index = rt*TK + kt; within a frag, lane l
// owns bytes l*16..+15 = MFMA operand row rt*16+(l&15), k octet (l>>4).
// ---------------------------------------------------------------------------

// Pipelined fragment GEMM, 4-wave (NW=4) variant sized for 2 blocks/CU:
// 3-slot LDS ring (24 KB slots -> 72 KB), depth-2 prefetch, counted vmcnt
// ladder (L -> 0), per-phase {ds_read || stage -> barrier -> lgkmcnt(0) ->
// setprio(1) MFMA setprio(0) -> barrier}.  Cross-block TLP (2 blocks/CU)
// hides fill/drain/barrier-skew.  Callers guarantee no other VMEM op is
// outstanding when the counted waits execute.
template <int AF, int BF, int WM, int WN, int KC, int PH, int KIT, int NW>
__device__ __forceinline__ void fgemm_p(
    const char* __restrict__ A, int rtA0, int TKA,
    const char* __restrict__ B, int rtB0, int TKB,
    char* lds, floatx4 (&acc)[AF / WM][BF / WN])
{
  constexpr int AWF  = AF / WM, BWF = BF / WN;
  constexpr int SLOT = (AF + BF) * KC * 1024;
  constexpr int L    = KC * (AF / NW + BF / NW);  // gll16 per wave per slot
  constexpr int AC   = AWF / PH;                  // A-frag rows per phase
  static_assert(KIT >= 3, "pipeline needs >=3 K-steps");
  static_assert(AF % NW == 0 && BF % NW == 0, "frag rows must divide waves");
  static_assert(AWF % PH == 0 && L % PH == 0, "phase split must divide");
  const int tid = threadIdx.x;
  const int w = tid >> 6, l = tid & 63;
  const int wm = w % WM, wn = w / WM;

  auto stage_part = [&](char* dst, int kt, int p) {
#pragma unroll
    for (int g = p * (L / PH); g < (p + 1) * (L / PH); ++g) {
      if (g < KC * (AF / NW)) {
        const int c = g / (AF / NW), q = g % (AF / NW);
        const int f = q * NW + w;
        gll16(A + (((size_t)(rtA0 + f) * TKA + kt * KC + c) << 10) + l * 16,
              dst + (c * AF + f) * 1024 + l * 16);
      } else {
        const int h = g - KC * (AF / NW);
        const int c = h / (BF / NW), q = h % (BF / NW);
        const int f = q * NW + w;
        gll16(B + (((size_t)(rtB0 + f) * TKB + kt * KC + c) << 10) + l * 16,
              dst + (KC * AF + c * BF + f) * 1024 + l * 16);
      }
    }
  };

  // Prologue: 2 slots in flight; publish slot 0 (wait only its L loads).
#pragma unroll
  for (int p = 0; p < PH; ++p) stage_part(lds, 0, p);
#pragma unroll
  for (int p = 0; p < PH; ++p) stage_part(lds + SLOT, 1, p);
  asm volatile("s_waitcnt vmcnt(%0) lgkmcnt(0)\ns_barrier" :: "n"(L) : "memory");

  short8 bf[KC][BWF];
  int cs = 0;                               // current ring slot (mod 3)
#pragma unroll 2
  for (int kt = 0; kt < KIT; ++kt) {
    const char* bA = lds + cs * SLOT;
    const char* bB = bA + KC * AF * 1024;
    int ns = cs - 1; if (ns < 0) ns = 2;    // slot of kt+2 == (cs+2)%3
    char* pdst = lds + ns * SLOT;
#pragma unroll
    for (int p = 0; p < PH; ++p) {
      short8 af[KC][AC];
#pragma unroll
      for (int c = 0; c < KC; ++c)
#pragma unroll
        for (int i = 0; i < AC; ++i)
          af[c][i] = *(const short8*)(bA + (c * AF + wm * AWF + p * AC + i) * 1024 + l * 16);
      if (p == 0) {
#pragma unroll
        for (int c = 0; c < KC; ++c)
#pragma unroll
          for (int j = 0; j < BWF; ++j)
            bf[c][j] = *(const short8*)(bB + (c * BF + wn * BWF + j) * 1024 + l * 16);
      }
      if (kt + 2 < KIT) stage_part(pdst, kt + 2, p);   // depth-2 prefetch

      asm volatile("s_barrier" ::: "memory");
      asm volatile("s_waitcnt lgkmcnt(0)" ::: "memory");
      __builtin_amdgcn_s_setprio(1);
#pragma unroll
      for (int c = 0; c < KC; ++c)
#pragma unroll
        for (int i = 0; i < AC; ++i)
#pragma unroll
          for (int j = 0; j < BWF; ++j)
            acc[p * AC + i][j] = __builtin_amdgcn_mfma_f32_16x16x32_bf16(
                af[c][i], bf[c][j], acc[p * AC + i][j], 0, 0, 0);
      __builtin_amdgcn_s_setprio(0);

      if (p == PH - 1) {        // slot-closing barrier: counted vmcnt ladder
        if (kt + 2 < KIT)
          asm volatile("s_waitcnt vmcnt(%0)\ns_barrier" :: "n"(L) : "memory");
        else if (kt + 1 < KIT)
          asm volatile("s_waitcnt vmcnt(0)\ns_barrier" ::: "memory");
        // last slot: fall through to epilogue (all gll16 retired by ladder)
      } else {
        asm volatile("s_barrier" ::: "memory");
      }
    }
    ++cs; if (cs == 3) cs = 0;
  }
}

// ---- K0: setup: X->XbF frags, W->WF frags (transposed) --------------------
__global__ __launch_bounds__(256) void setup_kernel(
    const float* __restrict__ X, const float* __restrict__ Wq,
    const float* __restrict__ Wk, const float* __restrict__ Wv,
    short8* __restrict__ XbF, short8* __restrict__ WF)
{
  const int flat = blockIdx.x * 256 + threadIdx.x;   // 0..524287
  {
    const int tile = flat >> 6, l = flat & 63;
    const int row = (tile >> 4) * 16 + (l & 15);
    const int k0  = (tile & 15) * 32 + (l >> 4) * 8;
    const float4 v0 = *(const float4*)(X + (size_t)row * DIM + k0);
    const float4 v1 = *(const float4*)(X + (size_t)row * DIM + k0 + 4);
    short8 o;
    o[0] = (short)f2b(v0.x); o[1] = (short)f2b(v0.y);
    o[2] = (short)f2b(v0.z); o[3] = (short)f2b(v0.w);
    o[4] = (short)f2b(v1.x); o[5] = (short)f2b(v1.y);
    o[6] = (short)f2b(v1.z); o[7] = (short)f2b(v1.w);
    XbF[flat] = o;
  }
  if (flat < 3 * 32768) {                            // W -> WF (rows=n, K=k)
    const int z = flat >> 15, within = flat & 32767;
    const float* W = (z == 0) ? Wq : (z == 1) ? Wk : Wv;
    const int tile = within >> 6, l = within & 63;
    const int n  = (tile >> 4) * 16 + (l & 15);
    const int k0 = (tile & 15) * 32 + (l >> 4) * 8;
    short8 o;
#pragma unroll
    for (int e = 0; e < 8; ++e)
      o[e] = (short)f2b(W[(size_t)(k0 + e) * DIM + n]);
    WF[flat] = o;
  }
}

// ---- K1: QKV. 256x128 tiles, 4 waves, 2 blocks/CU. Chunked XCD map. -------
// n<256: z=0,1: C[d][s] (A=WF 256d, B=XbF 128s). n>=256: C[s][d] (A=XbF 256s,
// B=WFv 128d).
__global__ __launch_bounds__(256, 2) void qkv_kernel(
    const short8* __restrict__ XbF, const short8* __restrict__ WF,
    const float* __restrict__ bq, const float* __restrict__ bk,
    const float* __restrict__ bv,
    unsigned short* __restrict__ QF, unsigned short* __restrict__ KF,
    unsigned short* __restrict__ VF)
{
  __shared__ char lds[73728];   // 3 x 24 KB ring
  const int blk = blockIdx.x;                    // 0..383
  const int n = (blk & 7) * 48 + (blk >> 3);     // chunked: 48 per XCD
  const int lane = threadIdx.x & 63, w = threadIdx.x >> 6;
  const int wm = w & 1, wn = w >> 1;             // WM=2, WN=2
  const char* Xc = (const char*)XbF;
  const char* Wc = (const char*)WF;
  floatx4 acc[8][4] = {};

  if (n < 256) {
    const int z = n >> 7, y = (n >> 6) & 1, x = n & 63;   // x: s-tile(128)
    fgemm_p<16, 8, 2, 2, 1, 2, 16, 4>(Wc + (size_t)z * 524288, y * 16, 16,
                                      Xc, x * 8, 16, lds, acc);
    const float* bias = z ? bk : bq;
    unsigned short* OF = z ? KF : QF;
    const int dbase = y * 256 + wm * 128;
    const int sbase = x * 128 + wn * 64;
#pragma unroll
    for (int i2 = 0; i2 < 8; ++i2) {
      const int d0 = dbase + i2 * 16 + (lane >> 4) * 4;
      const float4 b4 = *(const float4*)(bias + d0);
#pragma unroll
      for (int j = 0; j < 4; ++j) {
        const int s = sbase + j * 16 + (lane & 15);
        ushort4 pk;
        pk.x = f2b(acc[i2][j][0] + b4.x);
        pk.y = f2b(acc[i2][j][1] + b4.y);
        pk.z = f2b(acc[i2][j][2] + b4.z);
        pk.w = f2b(acc[i2][j][3] + b4.w);
        *(ushort4*)(OF + (size_t)((s >> 4) * 16 + (d0 >> 5)) * 512 +
                    ((((d0 & 31) >> 3) << 4) | (s & 15)) * 8 + (d0 & 7)) = pk;
      }
    }
  } else {
    const int m = n - 256;                         // 0..127
    const int x = m >> 2, y = m & 3;               // x: s-tile(256), y: d-tile(128)
    fgemm_p<16, 8, 2, 2, 1, 2, 16, 4>(Xc, x * 16, 16,
                                      Wc + 2 * 524288, y * 8, 16, lds, acc);
    const int sbase = x * 256 + wm * 128;
    const int dbase = y * 128 + wn * 64;
#pragma unroll
    for (int i2 = 0; i2 < 8; ++i2) {
      const int s0 = sbase + i2 * 16 + (lane >> 4) * 4;
      const int bt = s0 >> 11, t0 = s0 & 2047;
#pragma unroll
      for (int j = 0; j < 4; ++j) {
        const int d = dbase + j * 16 + (lane & 15);
        const float bn = bv[d];
        ushort4 pk;
        pk.x = f2b(acc[i2][j][0] + bn);
        pk.y = f2b(acc[i2][j][1] + bn);
        pk.z = f2b(acc[i2][j][2] + bn);
        pk.w = f2b(acc[i2][j][3] + bn);
        *(ushort4*)(VF + (size_t)bt * DIM * SEQ +
                    (size_t)((d >> 4) * 64 + (t0 >> 5)) * 512 +
                    ((((t0 & 31) >> 3) << 4) | (d & 15)) * 8 + (t0 & 7)) = pk;
      }
    }
  }
}

// ---- K2: S^T = K Q^T, 256t x 128s tiles; exp epilogue -> ScF + prow -------
// 512 blocks (2/CU). Chunked XCD map: 64/XCD => half a batch per XCD
// (Q panels + K panels ~3 MB, L2-resident).
__global__ __launch_bounds__(256, 2) void scores_kernel(
    const unsigned short* __restrict__ QF, const unsigned short* __restrict__ KF,
    unsigned short* __restrict__ ScF, float* __restrict__ prow)
{
  __shared__ char lds[73728];   // 3 x 24 KB ring
  const int blk = blockIdx.x;                    // 0..511
  const int n = (blk & 7) * 64 + (blk >> 3);
  const int b = n >> 7, t = n & 127;
  const int y = t >> 4, x = t & 15;              // y: t-tile(256), x: s-tile(128)
  const int lane = threadIdx.x & 63, w = threadIdx.x >> 6;
  const int wm = w & 1, wn = w >> 1;             // WM=2, WN=2
  floatx4 acc[8][4] = {};
  fgemm_p<16, 8, 2, 2, 1, 2, 16, 4>((const char*)KF + (size_t)b * 2097152, y * 16, 16,
                                    (const char*)QF + (size_t)b * 2097152, x * 8, 16,
                                    lds, acc);

  unsigned short* S = ScF + (size_t)b * SEQ * SEQ;
  const float scale = 0.044194173824159216f;  // 1/sqrt(512)
  const int tbase = y * 256 + wm * 128;
  const int sbase = x * 128 + wn * 64;
  float colsum[4] = {0.f, 0.f, 0.f, 0.f};
#pragma unroll
  for (int i2 = 0; i2 < 8; ++i2) {
    const int t0 = tbase + i2 * 16 + (lane >> 4) * 4;
#pragma unroll
    for (int j = 0; j < 4; ++j) {
      const int s = sbase + j * 16 + (lane & 15);
      float e0 = __expf(acc[i2][j][0] * scale);
      float e1 = __expf(acc[i2][j][1] * scale);
      float e2 = __expf(acc[i2][j][2] * scale);
      float e3 = __expf(acc[i2][j][3] * scale);
      colsum[j] += (e0 + e1) + (e2 + e3);
      ushort4 pk;
      pk.x = f2b(e0); pk.y = f2b(e1); pk.z = f2b(e2); pk.w = f2b(e3);
      *(ushort4*)(S + (size_t)((s >> 4) * 64 + (t0 >> 5)) * 512 +
                  ((((t0 & 31) >> 3) << 4) | (s & 15)) * 8 + (t0 & 7)) = pk;
    }
  }
#pragma unroll
  for (int j = 0; j < 4; ++j) {
    colsum[j] += __shfl_xor(colsum[j], 16, 64);
    colsum[j] += __shfl_xor(colsum[j], 32, 64);
  }
  if (lane < 16) {   // partial rowsum slice q = y*2+wm (t-range q*128..+127)
    float* dst = prow + ((size_t)(y * 2 + wm) * BATCH + b) * SEQ + sbase + lane;
#pragma unroll
    for (int j = 0; j < 4; ++j) dst[j * 16] = colsum[j];
  }
}

// ---- K3: out[s][d] = (ScF . VF) / rowsum[s]; 128s x 64d tile, BK=64 -------
// 512 blocks (2/CU). Chunked XCD map: 64/XCD => half batch (V L2-resident).
__global__ __launch_bounds__(256, 2) void pv_kernel(
    const unsigned short* __restrict__ ScF, const unsigned short* __restrict__ VF,
    const float* __restrict__ prow, float* __restrict__ out)
{
  __shared__ char lds[73728];   // 3 x 24 KB ring
  __shared__ float rinv[128];
  const int blk = blockIdx.x;                    // 0..511
  const int n = (blk & 7) * 64 + (blk >> 3);
  const int b = n >> 7, r = n & 127;
  const int x = r >> 3, y = r & 7;               // x: s-stripe(128), y: d-tile(64)
  const int t = threadIdx.x;
  if (t < 128) {   // rowsum = sum of 16 partial slices; drained before fgemm
    const int s = x * 128 + t;
    float rr = 0.f;
#pragma unroll
    for (int q = 0; q < 16; ++q) rr += prow[((size_t)q * BATCH + b) * SEQ + s];
    rinv[t] = 1.f / rr;
  }
  const int lane = threadIdx.x & 63, w = threadIdx.x >> 6;
  const int wm = w & 1, wn = w >> 1;             // WM=2, WN=2
  floatx4 acc[4][2] = {};
  fgemm_p<8, 4, 2, 2, 2, 1, 32, 4>((const char*)ScF + (size_t)b * 8388608, x * 8, 64,
                                   (const char*)VF + (size_t)b * 2097152, y * 4, 64,
                                   lds, acc);

  const int mbase = x * 128 + wm * 64;
  const int dbase = y * 64 + wn * 32;
#pragma unroll
  for (int i2 = 0; i2 < 4; ++i2) {
    const int r0 = wm * 64 + i2 * 16 + (lane >> 4) * 4;
    const int m0 = mbase + i2 * 16 + (lane >> 4) * 4;
    const float inv0 = rinv[r0], inv1 = rinv[r0 + 1], inv2 = rinv[r0 + 2], inv3 = rinv[r0 + 3];
#pragma unroll
    for (int j = 0; j < 2; ++j) {
      const int d = dbase + j * 16 + (lane & 15);
      float* o = out + ((size_t)b * SEQ + m0) * DIM + d;
      o[0 * DIM] = acc[i2][j][0] * inv0;
      o[1 * DIM] = acc[i2][j][1] * inv1;
      o[2 * DIM] = acc[i2][j][2] * inv2;
      o[3 * DIM] = acc[i2][j][3] * inv3;
    }
  }
}

extern "C" void kernel_launch(void* const* d_in, const int* in_sizes, int n_in,
                              void* d_out, int out_size, void* d_ws, size_t ws_size,
                              hipStream_t stream) {
  const float* X  = (const float*)d_in[0];
  const float* Wq = (const float*)d_in[1];
  const float* bq = (const float*)d_in[2];
  const float* Wk = (const float*)d_in[3];
  const float* bk = (const float*)d_in[4];
  const float* Wv = (const float*)d_in[5];
  const float* bv = (const float*)d_in[6];
  float* out = (float*)d_out;
  char* ws = (char*)d_ws;

  // workspace layout (bytes). prow aliases XbF (XbF dead after qkv; prow is
  // fully written by scores before pv reads it).
  short8* XbF = (short8*)(ws + 0);                    //  8 MB   (rows=b*S+s, K=512)
  float*  prow = (float*)(ws + 0);                    // 512 KB  [16][B][SEQ] partial rowsums
  short8* WF  = (short8*)(ws + 8388608);              //  1.5 MB (rows=n, K=512, x3)
  unsigned short* QF  = (unsigned short*)(ws + 9961472);   //  8 MB (rows=s, K=d)
  unsigned short* KF  = (unsigned short*)(ws + 18350080);  //  8 MB (rows=s, K=d)
  unsigned short* VF  = (unsigned short*)(ws + 26738688);  //  8 MB (rows=d, K=t, per b)
  unsigned short* ScF = (unsigned short*)(ws + 35127296);  // 32 MB (rows=s, K=t, per b)

  setup_kernel<<<dim3(2048), 256, 0, stream>>>(X, Wq, Wk, Wv, XbF, WF);
  qkv_kernel<<<dim3(384), 256, 0, stream>>>(XbF, WF, bq, bk, bv, QF, KF, VF);
  scores_kernel<<<dim3(512), 256, 0, stream>>>(QF, KF, ScF, prow);
  pv_kernel<<<dim3(512), 256, 0, stream>>>(ScF, VF, prow, out);
}

// Round 10
// 139.132 us; speedup vs baseline: 1.1481x; 1.0075x over previous
//
#include <hip/hip_runtime.h>
#include <hip/hip_bf16.h>
#include <stdint.h>

#define SEQ   2048
#define DIM   512
#define BATCH 4

typedef __attribute__((ext_vector_type(8))) short  short8;
typedef __attribute__((ext_vector_type(4))) float  floatx4;

static __device__ __forceinline__ unsigned short f2b(float f) {
  return __builtin_bit_cast(unsigned short, __float2bfloat16(f));
}

// async 16B/lane global->LDS (global_load_lds_dwordx4)
static __device__ __forceinline__ void gll16(const void* g, void* l) {
  __builtin_amdgcn_global_load_lds(
      (__attribute__((address_space(1))) void*)(uintptr_t)g,
      (__attribute__((address_space(3))) void*)l, 16, 0, 0);
}

// ---------------------------------------------------------------------------
// Fragment-linear layout (verified): logical [R rows][K] bf16 matrix as 1KB
// fragments of 16 rows x 32 k; frag index = rt*TK + kt; within a frag, lane l
// owns bytes l*16..+15 = MFMA operand row rt*16+(l&15), k octet (l>>4).
// ---------------------------------------------------------------------------

// Pipelined fragment GEMM (NW-wave): 3-slot LDS ring, depth-2 prefetch,
// counted vmcnt ladder (L -> 0), per-phase {ds_read || stage -> barrier ->
// lgkmcnt(0) -> setprio(1) MFMA setprio(0) -> barrier}.  Callers guarantee no
// other VMEM op is outstanding when the counted waits execute.
template <int AF, int BF, int WM, int WN, int KC, int PH, int KIT, int NW>
__device__ __forceinline__ void fgemm_p(
    const char* __restrict__ A, int rtA0, int TKA,
    const char* __restrict__ B, int rtB0, int TKB,
    char* lds, floatx4 (&acc)[AF / WM][BF / WN])
{
  constexpr int AWF  = AF / WM, BWF = BF / WN;
  constexpr int SLOT = (AF + BF) * KC * 1024;
  constexpr int L    = KC * (AF / NW + BF / NW);  // gll16 per wave per slot
  constexpr int AC   = AWF / PH;                  // A-frag rows per phase
  static_assert(KIT >= 3, "pipeline needs >=3 K-steps");
  static_assert(AF % NW == 0 && BF % NW == 0, "frag rows must divide waves");
  static_assert(AWF % PH == 0 && L % PH == 0, "phase split must divide");
  const int tid = threadIdx.x;
  const int w = tid >> 6, l = tid & 63;
  const int wm = w % WM, wn = w / WM;

  auto stage_part = [&](char* dst, int kt, int p) {
#pragma unroll
    for (int g = p * (L / PH); g < (p + 1) * (L / PH); ++g) {
      if (g < KC * (AF / NW)) {
        const int c = g / (AF / NW), q = g % (AF / NW);
        const int f = q * NW + w;
        gll16(A + (((size_t)(rtA0 + f) * TKA + kt * KC + c) << 10) + l * 16,
              dst + (c * AF + f) * 1024 + l * 16);
      } else {
        const int h = g - KC * (AF / NW);
        const int c = h / (BF / NW), q = h % (BF / NW);
        const int f = q * NW + w;
        gll16(B + (((size_t)(rtB0 + f) * TKB + kt * KC + c) << 10) + l * 16,
              dst + (KC * AF + c * BF + f) * 1024 + l * 16);
      }
    }
  };

  // Prologue: 2 slots in flight; publish slot 0 (wait only its L loads).
#pragma unroll
  for (int p = 0; p < PH; ++p) stage_part(lds, 0, p);
#pragma unroll
  for (int p = 0; p < PH; ++p) stage_part(lds + SLOT, 1, p);
  asm volatile("s_waitcnt vmcnt(%0) lgkmcnt(0)\ns_barrier" :: "n"(L) : "memory");

  short8 bf[KC][BWF];
  int cs = 0;                               // current ring slot (mod 3)
#pragma unroll 2
  for (int kt = 0; kt < KIT; ++kt) {
    const char* bA = lds + cs * SLOT;
    const char* bB = bA + KC * AF * 1024;
    int ns = cs - 1; if (ns < 0) ns = 2;    // slot of kt+2 == (cs+2)%3
    char* pdst = lds + ns * SLOT;
#pragma unroll
    for (int p = 0; p < PH; ++p) {
      short8 af[KC][AC];
#pragma unroll
      for (int c = 0; c < KC; ++c)
#pragma unroll
        for (int i = 0; i < AC; ++i)
          af[c][i] = *(const short8*)(bA + (c * AF + wm * AWF + p * AC + i) * 1024 + l * 16);
      if (p == 0) {
#pragma unroll
        for (int c = 0; c < KC; ++c)
#pragma unroll
          for (int j = 0; j < BWF; ++j)
            bf[c][j] = *(const short8*)(bB + (c * BF + wn * BWF + j) * 1024 + l * 16);
      }
      if (kt + 2 < KIT) stage_part(pdst, kt + 2, p);   // depth-2 prefetch

      asm volatile("s_barrier" ::: "memory");
      asm volatile("s_waitcnt lgkmcnt(0)" ::: "memory");
      __builtin_amdgcn_s_setprio(1);
#pragma unroll
      for (int c = 0; c < KC; ++c)
#pragma unroll
        for (int i = 0; i < AC; ++i)
#pragma unroll
          for (int j = 0; j < BWF; ++j)
            acc[p * AC + i][j] = __builtin_amdgcn_mfma_f32_16x16x32_bf16(
                af[c][i], bf[c][j], acc[p * AC + i][j], 0, 0, 0);
      __builtin_amdgcn_s_setprio(0);

      if (p == PH - 1) {        // slot-closing barrier: counted vmcnt ladder
        if (kt + 2 < KIT)
          asm volatile("s_waitcnt vmcnt(%0)\ns_barrier" :: "n"(L) : "memory");
        else if (kt + 1 < KIT)
          asm volatile("s_waitcnt vmcnt(0)\ns_barrier" ::: "memory");
        // last slot: fall through to epilogue (all gll16 retired by ladder)
      } else {
        asm volatile("s_barrier" ::: "memory");
      }
    }
    ++cs; if (cs == 3) cs = 0;
  }
}

// ---- K0: setup: X->XbF frags, W->WF frags (transposed) --------------------
__global__ __launch_bounds__(256) void setup_kernel(
    const float* __restrict__ X, const float* __restrict__ Wq,
    const float* __restrict__ Wk, const float* __restrict__ Wv,
    short8* __restrict__ XbF, short8* __restrict__ WF)
{
  const int flat = blockIdx.x * 256 + threadIdx.x;   // 0..524287
  {
    const int tile = flat >> 6, l = flat & 63;
    const int row = (tile >> 4) * 16 + (l & 15);
    const int k0  = (tile & 15) * 32 + (l >> 4) * 8;
    const float4 v0 = *(const float4*)(X + (size_t)row * DIM + k0);
    const float4 v1 = *(const float4*)(X + (size_t)row * DIM + k0 + 4);
    short8 o;
    o[0] = (short)f2b(v0.x); o[1] = (short)f2b(v0.y);
    o[2] = (short)f2b(v0.z); o[3] = (short)f2b(v0.w);
    o[4] = (short)f2b(v1.x); o[5] = (short)f2b(v1.y);
    o[6] = (short)f2b(v1.z); o[7] = (short)f2b(v1.w);
    XbF[flat] = o;
  }
  if (flat < 3 * 32768) {                            // W -> WF (rows=n, K=k)
    const int z = flat >> 15, within = flat & 32767;
    const float* W = (z == 0) ? Wq : (z == 1) ? Wk : Wv;
    const int tile = within >> 6, l = within & 63;
    const int n  = (tile >> 4) * 16 + (l & 15);
    const int k0 = (tile & 15) * 32 + (l >> 4) * 8;
    short8 o;
#pragma unroll
    for (int e = 0; e < 8; ++e)
      o[e] = (short)f2b(W[(size_t)(k0 + e) * DIM + n]);
    WF[flat] = o;
  }
}

// ---- K1: QKV. 256x128 tiles, 4 waves, 2 blocks/CU. Chunked XCD map. -------
__global__ __launch_bounds__(256, 2) void qkv_kernel(
    const short8* __restrict__ XbF, const short8* __restrict__ WF,
    const float* __restrict__ bq, const float* __restrict__ bk,
    const float* __restrict__ bv,
    unsigned short* __restrict__ QF, unsigned short* __restrict__ KF,
    unsigned short* __restrict__ VF)
{
  __shared__ char lds[73728];   // 3 x 24 KB ring
  const int blk = blockIdx.x;                    // 0..383
  const int n = (blk & 7) * 48 + (blk >> 3);     // chunked: 48 per XCD
  const int lane = threadIdx.x & 63, w = threadIdx.x >> 6;
  const int wm = w & 1, wn = w >> 1;             // WM=2, WN=2
  const char* Xc = (const char*)XbF;
  const char* Wc = (const char*)WF;
  floatx4 acc[8][4] = {};

  if (n < 256) {
    const int z = n >> 7, y = (n >> 6) & 1, x = n & 63;   // x: s-tile(128)
    fgemm_p<16, 8, 2, 2, 1, 2, 16, 4>(Wc + (size_t)z * 524288, y * 16, 16,
                                      Xc, x * 8, 16, lds, acc);
    const float* bias = z ? bk : bq;
    unsigned short* OF = z ? KF : QF;
    const int dbase = y * 256 + wm * 128;
    const int sbase = x * 128 + wn * 64;
#pragma unroll
    for (int i2 = 0; i2 < 8; ++i2) {
      const int d0 = dbase + i2 * 16 + (lane >> 4) * 4;
      const float4 b4 = *(const float4*)(bias + d0);
#pragma unroll
      for (int j = 0; j < 4; ++j) {
        const int s = sbase + j * 16 + (lane & 15);
        ushort4 pk;
        pk.x = f2b(acc[i2][j][0] + b4.x);
        pk.y = f2b(acc[i2][j][1] + b4.y);
        pk.z = f2b(acc[i2][j][2] + b4.z);
        pk.w = f2b(acc[i2][j][3] + b4.w);
        *(ushort4*)(OF + (size_t)((s >> 4) * 16 + (d0 >> 5)) * 512 +
                    ((((d0 & 31) >> 3) << 4) | (s & 15)) * 8 + (d0 & 7)) = pk;
      }
    }
  } else {
    const int m = n - 256;                         // 0..127
    const int x = m >> 2, y = m & 3;               // x: s-tile(256), y: d-tile(128)
    fgemm_p<16, 8, 2, 2, 1, 2, 16, 4>(Xc, x * 16, 16,
                                      Wc + 2 * 524288, y * 8, 16, lds, acc);
    const int sbase = x * 256 + wm * 128;
    const int dbase = y * 128 + wn * 64;
#pragma unroll
    for (int i2 = 0; i2 < 8; ++i2) {
      const int s0 = sbase + i2 * 16 + (lane >> 4) * 4;
      const int bt = s0 >> 11, t0 = s0 & 2047;
#pragma unroll
      for (int j = 0; j < 4; ++j) {
        const int d = dbase + j * 16 + (lane & 15);
        const float bn = bv[d];
        ushort4 pk;
        pk.x = f2b(acc[i2][j][0] + bn);
        pk.y = f2b(acc[i2][j][1] + bn);
        pk.z = f2b(acc[i2][j][2] + bn);
        pk.w = f2b(acc[i2][j][3] + bn);
        *(ushort4*)(VF + (size_t)bt * DIM * SEQ +
                    (size_t)((d >> 4) * 64 + (t0 >> 5)) * 512 +
                    ((((t0 & 31) >> 3) << 4) | (d & 15)) * 8 + (t0 & 7)) = pk;
      }
    }
  }
}

// ---- K2: S^T = K Q^T, 256t x 128s tiles; exp epilogue -> ScF + prow -------
// 512 blocks (2/CU). Chunked XCD map: 64/XCD => half a batch per XCD.
__global__ __launch_bounds__(256, 2) void scores_kernel(
    const unsigned short* __restrict__ QF, const unsigned short* __restrict__ KF,
    unsigned short* __restrict__ ScF, float* __restrict__ prow)
{
  __shared__ char lds[73728];   // 3 x 24 KB ring
  const int blk = blockIdx.x;                    // 0..511
  const int n = (blk & 7) * 64 + (blk >> 3);
  const int b = n >> 7, t = n & 127;
  const int y = t >> 4, x = t & 15;              // y: t-tile(256), x: s-tile(128)
  const int lane = threadIdx.x & 63, w = threadIdx.x >> 6;
  const int wm = w & 1, wn = w >> 1;             // WM=2, WN=2
  floatx4 acc[8][4] = {};
  fgemm_p<16, 8, 2, 2, 1, 2, 16, 4>((const char*)KF + (size_t)b * 2097152, y * 16, 16,
                                    (const char*)QF + (size_t)b * 2097152, x * 8, 16,
                                    lds, acc);

  unsigned short* S = ScF + (size_t)b * SEQ * SEQ;
  const float scale = 0.044194173824159216f;  // 1/sqrt(512)
  const int tbase = y * 256 + wm * 128;
  const int sbase = x * 128 + wn * 64;
  float colsum[4] = {0.f, 0.f, 0.f, 0.f};
#pragma unroll
  for (int i2 = 0; i2 < 8; ++i2) {
    const int t0 = tbase + i2 * 16 + (lane >> 4) * 4;
#pragma unroll
    for (int j = 0; j < 4; ++j) {
      const int s = sbase + j * 16 + (lane & 15);
      float e0 = __expf(acc[i2][j][0] * scale);
      float e1 = __expf(acc[i2][j][1] * scale);
      float e2 = __expf(acc[i2][j][2] * scale);
      float e3 = __expf(acc[i2][j][3] * scale);
      colsum[j] += (e0 + e1) + (e2 + e3);
      ushort4 pk;
      pk.x = f2b(e0); pk.y = f2b(e1); pk.z = f2b(e2); pk.w = f2b(e3);
      *(ushort4*)(S + (size_t)((s >> 4) * 64 + (t0 >> 5)) * 512 +
                  ((((t0 & 31) >> 3) << 4) | (s & 15)) * 8 + (t0 & 7)) = pk;
    }
  }
#pragma unroll
  for (int j = 0; j < 4; ++j) {
    colsum[j] += __shfl_xor(colsum[j], 16, 64);
    colsum[j] += __shfl_xor(colsum[j], 32, 64);
  }
  if (lane < 16) {   // partial rowsum slice q = y*2+wm (t-range q*128..+127)
    float* dst = prow + ((size_t)(y * 2 + wm) * BATCH + b) * SEQ + sbase + lane;
#pragma unroll
    for (int j = 0; j < 4; ++j) dst[j * 16] = colsum[j];
  }
}

// ---- K3: out[s][d] = (ScF . VF) / rowsum[s]; 128s x 128d tile, 8 waves. ---
// 256 blocks, 1/CU. Staged bytes 262 MB vs r5 pv's 393 MB (-33%): the r6 pv
// half, isolated (single-variable A/B vs r9 = decomposes r6's confound).
// Chunked XCD: 32/XCD -> b = xcd/2; Sc s-stripe's 4 d-consumers co-XCD.
__global__ __launch_bounds__(512, 2) void pv_kernel(
    const unsigned short* __restrict__ ScF, const unsigned short* __restrict__ VF,
    const float* __restrict__ prow, float* __restrict__ out)
{
  __shared__ char lds[98304];   // 3 x 32 KB ring
  __shared__ float rinv[128];
  const int blk = blockIdx.x;                    // 0..255
  const int n = (blk & 7) * 32 + (blk >> 3);
  const int b = n >> 6, x = (n >> 2) & 15, y = n & 3;
  const int t = threadIdx.x;
  if (t < 128) {   // rowsum = sum of 16 partial slices (pre-pass loads only
    const int s = x * 128 + t;   // make the counted waits conservative)
    float rr = 0.f;
#pragma unroll
    for (int q = 0; q < 16; ++q) rr += prow[((size_t)q * BATCH + b) * SEQ + s];
    rinv[t] = 1.f / rr;
  }
  const int lane = threadIdx.x & 63, w = threadIdx.x >> 6;
  const int wm = w & 1, wn = w >> 1;             // WM=2, WN=4
  floatx4 acc[4][2] = {};
  fgemm_p<8, 8, 2, 4, 2, 1, 32, 8>((const char*)ScF + (size_t)b * 8388608, x * 8, 64,
                                   (const char*)VF + (size_t)b * 2097152, y * 8, 64,
                                   lds, acc);

  const int mbase = x * 128 + wm * 64;
  const int dbase = y * 128 + wn * 32;
#pragma unroll
  for (int i2 = 0; i2 < 4; ++i2) {
    const int r0 = wm * 64 + i2 * 16 + (lane >> 4) * 4;
    const int m0 = mbase + i2 * 16 + (lane >> 4) * 4;
    const float inv0 = rinv[r0], inv1 = rinv[r0 + 1], inv2 = rinv[r0 + 2], inv3 = rinv[r0 + 3];
#pragma unroll
    for (int j = 0; j < 2; ++j) {
      const int d = dbase + j * 16 + (lane & 15);
      float* o = out + ((size_t)b * SEQ + m0) * DIM + d;
      o[0 * DIM] = acc[i2][j][0] * inv0;
      o[1 * DIM] = acc[i2][j][1] * inv1;
      o[2 * DIM] = acc[i2][j][2] * inv2;
      o[3 * DIM] = acc[i2][j][3] * inv3;
    }
  }
}

extern "C" void kernel_launch(void* const* d_in, const int* in_sizes, int n_in,
                              void* d_out, int out_size, void* d_ws, size_t ws_size,
                              hipStream_t stream) {
  const float* X  = (const float*)d_in[0];
  const float* Wq = (const float*)d_in[1];
  const float* bq = (const float*)d_in[2];
  const float* Wk = (const float*)d_in[3];
  const float* bk = (const float*)d_in[4];
  const float* Wv = (const float*)d_in[5];
  const float* bv = (const float*)d_in[6];
  float* out = (float*)d_out;
  char* ws = (char*)d_ws;

  // workspace layout (bytes). prow aliases XbF (XbF dead after qkv; prow is
  // fully written by scores before pv reads it).
  short8* XbF = (short8*)(ws + 0);                    //  8 MB   (rows=b*S+s, K=512)
  float*  prow = (float*)(ws + 0);                    // 512 KB  [16][B][SEQ] partial rowsums
  short8* WF  = (short8*)(ws + 8388608);              //  1.5 MB (rows=n, K=512, x3)
  unsigned short* QF  = (unsigned short*)(ws + 9961472);   //  8 MB (rows=s, K=d)
  unsigned short* KF  = (unsigned short*)(ws + 18350080);  //  8 MB (rows=s, K=d)
  unsigned short* VF  = (unsigned short*)(ws + 26738688);  //  8 MB (rows=d, K=t, per b)
  unsigned short* ScF = (unsigned short*)(ws + 35127296);  // 32 MB (rows=s, K=t, per b)

  setup_kernel<<<dim3(2048), 256, 0, stream>>>(X, Wq, Wk, Wv, XbF, WF);
  qkv_kernel<<<dim3(384), 256, 0, stream>>>(XbF, WF, bq, bk, bv, QF, KF, VF);
  scores_kernel<<<dim3(512), 256, 0, stream>>>(QF, KF, ScF, prow);
  pv_kernel<<<dim3(256), 512, 0, stream>>>(ScF, VF, prow, out);
}